// Round 2
// baseline (946.313 us; speedup 1.0000x reference)
//
#include <hip/hip_runtime.h>
#include <cstdint>
#include <cstddef>

// Problem constants (from setup_inputs)
#define T_TOK 8192
#define HDIM  2048
#define NEXP  8
#define IDIM  1024
#define CAP   17408   // 16384 assignments + 8*127 padding, rounded to 128
#define NTILE (CAP / 128)   // 136 padded slot-tiles max

typedef __attribute__((ext_vector_type(8))) __bf16 bf16x8;
typedef __attribute__((ext_vector_type(4))) __bf16 bf16x4;
typedef __attribute__((ext_vector_type(4))) float  f32x4;

// async global->LDS, 16B/lane. LDS dest = wave-uniform base + lane*16.
#define GLDS16(g, l)                                                        \
  __builtin_amdgcn_global_load_lds(                                         \
      (__attribute__((address_space(1))) void*)(g),                         \
      (__attribute__((address_space(3))) void*)(l), 16, 0, 0)

// ---------------------------------------------------------------------------
// fp32 -> bf16 bulk convert (weights)
__global__ __launch_bounds__(256) void cvt_k(const float* __restrict__ src,
                                             __bf16* __restrict__ dst, int n4) {
  int i = blockIdx.x * blockDim.x + threadIdx.x;
  int stride = gridDim.x * blockDim.x;
  for (; i < n4; i += stride) {
    float4 v = ((const float4*)src)[i];
    bf16x4 b;
    b[0] = (__bf16)v.x; b[1] = (__bf16)v.y; b[2] = (__bf16)v.z; b[3] = (__bf16)v.w;
    ((bf16x4*)dst)[i] = b;
  }
}

// ---------------------------------------------------------------------------
// Router: one wave per token. fp64 logits, top-2, renormalized weights.
// Also emits bf16 copy of x.
__global__ __launch_bounds__(256) void router_k(
    const float* __restrict__ x, const float* __restrict__ wg,
    __bf16* __restrict__ xb, int* __restrict__ tok_idx,
    float* __restrict__ tok_w, int* __restrict__ counts) {
  int gid  = blockIdx.x * blockDim.x + threadIdx.x;
  int t    = gid >> 6;
  int lane = gid & 63;
  if (t >= T_TOK) return;

  const float4* x4 = (const float4*)(x + (size_t)t * HDIM);
  bf16x4* xb4 = (bf16x4*)(xb + (size_t)t * HDIM);

  double acc[NEXP];
#pragma unroll
  for (int e = 0; e < NEXP; ++e) acc[e] = 0.0;

#pragma unroll
  for (int j = 0; j < 8; ++j) {
    int idx = j * 64 + lane;            // float4 index (512 per row)
    float4 xv = x4[idx];
    bf16x4 b;
    b[0] = (__bf16)xv.x; b[1] = (__bf16)xv.y; b[2] = (__bf16)xv.z; b[3] = (__bf16)xv.w;
    xb4[idx] = b;
#pragma unroll
    for (int e = 0; e < NEXP; ++e) {
      float4 wv = ((const float4*)(wg + (size_t)e * HDIM))[idx];
      acc[e] += (double)xv.x * wv.x + (double)xv.y * wv.y +
                (double)xv.z * wv.z + (double)xv.w * wv.w;
    }
  }
#pragma unroll
  for (int off = 32; off > 0; off >>= 1)
#pragma unroll
    for (int e = 0; e < NEXP; ++e) acc[e] += __shfl_xor(acc[e], off, 64);

  if (lane == 0) {
    int i0 = 0; double m0 = acc[0];
    for (int e = 1; e < NEXP; ++e) if (acc[e] > m0) { m0 = acc[e]; i0 = e; }
    int i1 = -1; double m1 = -1e300;
    for (int e = 0; e < NEXP; ++e)
      if (e != i0 && acc[e] > m1) { m1 = acc[e]; i1 = e; }
    // softmax denominators cancel in the renorm: w0 = 1/(1+exp(l1-l0))
    double p0 = 1.0 / (1.0 + exp(m1 - m0));
    tok_idx[t * 2 + 0] = i0;  tok_idx[t * 2 + 1] = i1;
    tok_w[t * 2 + 0] = (float)p0;
    tok_w[t * 2 + 1] = (float)(1.0 - p0);
    atomicAdd(&counts[i0], 1);
    atomicAdd(&counts[i1], 1);
  }
}

// ---------------------------------------------------------------------------
// Padded exclusive scan of counts. offp[NEXP] = total padded slots.
__global__ void offsets_k(const int* __restrict__ counts, int* __restrict__ offp,
                          int* __restrict__ ctr2) {
  if (threadIdx.x == 0) {
    int off = 0;
    for (int e = 0; e < NEXP; ++e) { offp[e] = off; off += (counts[e] + 127) & ~127; }
    offp[NEXP] = off;
  }
  if (threadIdx.x < NEXP) ctr2[threadIdx.x] = 0;
}

// Scatter token ids / weights into per-expert buckets; record slot per (t,k)
__global__ __launch_bounds__(256) void assign_k(
    const int* __restrict__ tok_idx, const float* __restrict__ tok_w,
    const int* __restrict__ offp, int* __restrict__ ctr2,
    int* __restrict__ btok, float* __restrict__ bw, int* __restrict__ pos_of) {
  int t = blockIdx.x * blockDim.x + threadIdx.x;
  if (t >= T_TOK) return;
#pragma unroll
  for (int k = 0; k < 2; ++k) {
    int e = tok_idx[t * 2 + k];
    int p = atomicAdd(&ctr2[e], 1);
    int pos = offp[e] + p;
    btok[pos] = t;
    bw[pos] = tok_w[t * 2 + k];
    pos_of[t * 2 + k] = pos;
  }
}

// ---------------------------------------------------------------------------
// Map a padded-slot tile (128 rows) to its expert. Returns -1 if out of range.
__device__ __forceinline__ int tile_expert(const int* offp, int slot0) {
  if (slot0 >= offp[NEXP]) return -1;
  int e = 0;
#pragma unroll
  for (int i = 1; i < NEXP; ++i) if (offp[i] <= slot0) e = i;
  return e;
}

// ---------------------------------------------------------------------------
// m97-structure GEMM: gathered X [128 x K2048] x W-rows tile [128 x K] -> acc.
// gemm_g: writes g (fp32). gemm_u: epilogue h = silu(g)*u (bf16).
template <bool FUSE_SILU>
__global__ __launch_bounds__(256) void gemm1_k(
    const __bf16* __restrict__ xb, const __bf16* __restrict__ wb,
    float* __restrict__ g, __bf16* __restrict__ h,
    const int* __restrict__ btok, const int* __restrict__ counts,
    const int* __restrict__ offp) {
  const int mt    = blockIdx.y;
  const int slot0 = mt * 128;
  const int e     = tile_expert(offp, slot0);
  if (e < 0) return;
  const int cnt  = counts[e];
  const int base = offp[e];
  const int mrow = slot0 - base;          // multiple of 128 within expert
  const int it   = blockIdx.x;            // 128 i-values per block

  __shared__ __align__(16) __bf16 As[128 * 32];
  __shared__ __align__(16) __bf16 Bs[128 * 32];

  const int tid  = threadIdx.x;
  const int lane = tid & 63;
  const int wid  = tid >> 6;
  const int wy   = wid >> 1, wx = wid & 1;

  // staging: 4 lanes/row, 16B each -> 64 rows per issue, 2 issues per tile
  const int r0 = tid >> 2;
  const int c8 = (tid & 3) * 8;
  int ma = mrow + r0, mb = ma + 64;
  int toka = btok[base + (ma < cnt ? ma : cnt - 1)];
  int tokb = btok[base + (mb < cnt ? mb : cnt - 1)];
  const __bf16* pA0 = xb + (size_t)toka * HDIM + c8;
  const __bf16* pA1 = xb + (size_t)tokb * HDIM + c8;
  const __bf16* pB0 = wb + ((size_t)e * IDIM + it * 128 + r0) * HDIM + c8;
  const __bf16* pB1 = pB0 + (size_t)64 * HDIM;

  const int wbase = wid * 512;  // wave covers 16 rows x 32 elems
  __bf16* lA0 = As + wbase;  __bf16* lA1 = As + 2048 + wbase;
  __bf16* lB0 = Bs + wbase;  __bf16* lB1 = Bs + 2048 + wbase;

  f32x4 acc[4][4] = {};
  const int frow = lane & 15;
  const int fk   = (lane >> 4) * 8;

  for (int kt = 0; kt < HDIM / 32; ++kt) {
    GLDS16(pA0, lA0); GLDS16(pA1, lA1);
    GLDS16(pB0, lB0); GLDS16(pB1, lB1);
    pA0 += 32; pA1 += 32; pB0 += 32; pB1 += 32;
    __syncthreads();

    bf16x8 af[4], bf[4];
#pragma unroll
    for (int mf = 0; mf < 4; ++mf)
      af[mf] = *(const bf16x8*)&As[(wy * 64 + mf * 16 + frow) * 32 + fk];
#pragma unroll
    for (int nf = 0; nf < 4; ++nf)
      bf[nf] = *(const bf16x8*)&Bs[(wx * 64 + nf * 16 + frow) * 32 + fk];
#pragma unroll
    for (int mf = 0; mf < 4; ++mf)
#pragma unroll
      for (int nf = 0; nf < 4; ++nf)
        acc[mf][nf] = __builtin_amdgcn_mfma_f32_16x16x32_bf16(af[mf], bf[nf], acc[mf][nf], 0, 0, 0);
    __syncthreads();
  }

  const int i0c = it * 128 + wx * 64;
#pragma unroll
  for (int mf = 0; mf < 4; ++mf) {
    const int sbase = slot0 + wy * 64 + mf * 16 + (lane >> 4) * 4;
#pragma unroll
    for (int nf = 0; nf < 4; ++nf) {
      const int ic = i0c + nf * 16 + (lane & 15);
#pragma unroll
      for (int ri = 0; ri < 4; ++ri) {
        size_t idx = (size_t)(sbase + ri) * IDIM + ic;
        if (FUSE_SILU) {
          float gv = g[idx];
          float s  = gv / (1.0f + __expf(-gv)) * acc[mf][nf][ri];
          h[idx] = (__bf16)s;
        } else {
          g[idx] = acc[mf][nf][ri];
        }
      }
    }
  }
}

// ---------------------------------------------------------------------------
// GEMM2: h [128 x K1024] x w2 tile [128 x K1024] -> y[slot] = w * acc (bf16)
__global__ __launch_bounds__(256) void gemm2_k(
    const __bf16* __restrict__ h, const __bf16* __restrict__ w2b,
    __bf16* __restrict__ y, const float* __restrict__ bw,
    const int* __restrict__ offp) {
  const int mt    = blockIdx.y;
  const int slot0 = mt * 128;
  const int e     = tile_expert(offp, slot0);
  if (e < 0) return;
  const int nt = blockIdx.x;     // 128 H-cols per block

  __shared__ __align__(16) __bf16 As[128 * 32];
  __shared__ __align__(16) __bf16 Bs[128 * 32];

  const int tid  = threadIdx.x;
  const int lane = tid & 63;
  const int wid  = tid >> 6;
  const int wy   = wid >> 1, wx = wid & 1;

  const int r0 = tid >> 2;
  const int c8 = (tid & 3) * 8;
  const __bf16* pA0 = h + ((size_t)slot0 + r0) * IDIM + c8;
  const __bf16* pA1 = pA0 + (size_t)64 * IDIM;
  const __bf16* pB0 = w2b + ((size_t)e * HDIM + nt * 128 + r0) * IDIM + c8;
  const __bf16* pB1 = pB0 + (size_t)64 * IDIM;

  const int wbase = wid * 512;
  __bf16* lA0 = As + wbase;  __bf16* lA1 = As + 2048 + wbase;
  __bf16* lB0 = Bs + wbase;  __bf16* lB1 = Bs + 2048 + wbase;

  f32x4 acc[4][4] = {};
  const int frow = lane & 15;
  const int fk   = (lane >> 4) * 8;

  for (int kt = 0; kt < IDIM / 32; ++kt) {
    GLDS16(pA0, lA0); GLDS16(pA1, lA1);
    GLDS16(pB0, lB0); GLDS16(pB1, lB1);
    pA0 += 32; pA1 += 32; pB0 += 32; pB1 += 32;
    __syncthreads();

    bf16x8 af[4], bf[4];
#pragma unroll
    for (int mf = 0; mf < 4; ++mf)
      af[mf] = *(const bf16x8*)&As[(wy * 64 + mf * 16 + frow) * 32 + fk];
#pragma unroll
    for (int nf = 0; nf < 4; ++nf)
      bf[nf] = *(const bf16x8*)&Bs[(wx * 64 + nf * 16 + frow) * 32 + fk];
#pragma unroll
    for (int mf = 0; mf < 4; ++mf)
#pragma unroll
      for (int nf = 0; nf < 4; ++nf)
        acc[mf][nf] = __builtin_amdgcn_mfma_f32_16x16x32_bf16(af[mf], bf[nf], acc[mf][nf], 0, 0, 0);
    __syncthreads();
  }

  const int ncol = nt * 128 + wx * 64;
#pragma unroll
  for (int mf = 0; mf < 4; ++mf) {
    const int sbase = slot0 + wy * 64 + mf * 16 + (lane >> 4) * 4;
#pragma unroll
    for (int ri = 0; ri < 4; ++ri) {
      int s = sbase + ri;
      float w = bw[s];   // padded slots: poison but finite; never combined
#pragma unroll
      for (int nf = 0; nf < 4; ++nf) {
        int c = ncol + nf * 16 + (lane & 15);
        y[(size_t)s * HDIM + c] = (__bf16)(acc[mf][nf][ri] * w);
      }
    }
  }
}

// ---------------------------------------------------------------------------
// out[t] = y[pos0[t]] + y[pos1[t]]   (one block per token, 8 cols/thread)
__global__ __launch_bounds__(256) void combine_k(
    const __bf16* __restrict__ y, const int* __restrict__ pos_of,
    float* __restrict__ out) {
  const int t  = blockIdx.x;
  const int c8 = threadIdx.x * 8;
  const int p0 = pos_of[t * 2 + 0];
  const int p1 = pos_of[t * 2 + 1];
  bf16x8 a = *(const bf16x8*)&y[(size_t)p0 * HDIM + c8];
  bf16x8 b = *(const bf16x8*)&y[(size_t)p1 * HDIM + c8];
  float4 o0, o1;
  o0.x = (float)a[0] + (float)b[0];  o0.y = (float)a[1] + (float)b[1];
  o0.z = (float)a[2] + (float)b[2];  o0.w = (float)a[3] + (float)b[3];
  o1.x = (float)a[4] + (float)b[4];  o1.y = (float)a[5] + (float)b[5];
  o1.z = (float)a[6] + (float)b[6];  o1.w = (float)a[7] + (float)b[7];
  float* op = out + (size_t)t * HDIM + c8;
  *(float4*)op = o0;
  *(float4*)(op + 4) = o1;
}

// ---------------------------------------------------------------------------
extern "C" void kernel_launch(void* const* d_in, const int* in_sizes, int n_in,
                              void* d_out, int out_size, void* d_ws, size_t ws_size,
                              hipStream_t stream) {
  (void)in_sizes; (void)n_in; (void)out_size; (void)ws_size;
  const float* x  = (const float*)d_in[0];
  const float* wg = (const float*)d_in[1];
  const float* w1 = (const float*)d_in[2];
  const float* w3 = (const float*)d_in[3];
  const float* w2 = (const float*)d_in[4];
  float* out = (float*)d_out;

  char* ws = (char*)d_ws;
  size_t off = 0;
  auto alloc = [&](size_t bytes) -> char* {
    char* p = ws + off;
    off += (bytes + 255) & ~(size_t)255;
    return p;
  };
  __bf16* xb      = (__bf16*)alloc((size_t)T_TOK * HDIM * 2);          // 33.5 MB
  __bf16* w1b     = (__bf16*)alloc((size_t)NEXP * IDIM * HDIM * 2);    // 33.5 MB
  __bf16* w3b     = (__bf16*)alloc((size_t)NEXP * IDIM * HDIM * 2);    // 33.5 MB
  float*  g       = (float*)alloc((size_t)CAP * IDIM * 4);             // 71.4 MB
  __bf16* w2b     = (__bf16*)alloc((size_t)NEXP * HDIM * IDIM * 2);    // 33.5 MB
  __bf16* h       = (__bf16*)alloc((size_t)CAP * IDIM * 2);            // 35.7 MB
  int*    btok    = (int*)alloc((size_t)CAP * 4);
  float*  bw      = (float*)alloc((size_t)CAP * 4);
  int*    pos_of  = (int*)alloc((size_t)T_TOK * 2 * 4);
  int*    tok_idx = (int*)alloc((size_t)T_TOK * 2 * 4);
  float*  tok_w   = (float*)alloc((size_t)T_TOK * 2 * 4);
  int*    counts  = (int*)alloc(256);
  int*    ctr2    = (int*)alloc(256);
  int*    offp    = (int*)alloc(256);
  // y (CAP*HDIM bf16 = 71.3 MB) aliases [w1b .. w3b .. g) — all dead by gemm2.
  __bf16* y = (__bf16*)w1b;
  // total ws ≈ 242 MB

  hipMemsetAsync(counts, 0, 768, stream);                 // counts+ctr2+offp

  const int n4w = NEXP * IDIM * HDIM / 4;
  cvt_k<<<2048, 256, 0, stream>>>(w1, w1b, n4w);
  cvt_k<<<2048, 256, 0, stream>>>(w3, w3b, n4w);
  cvt_k<<<2048, 256, 0, stream>>>(w2, w2b, n4w);

  router_k<<<T_TOK / 4, 256, 0, stream>>>(x, wg, xb, tok_idx, tok_w, counts);
  offsets_k<<<1, 64, 0, stream>>>(counts, offp, ctr2);
  assign_k<<<T_TOK / 256, 256, 0, stream>>>(tok_idx, tok_w, offp, ctr2, btok, bw, pos_of);

  gemm1_k<false><<<dim3(IDIM / 128, NTILE), 256, 0, stream>>>(xb, w1b, g, h, btok, counts, offp);
  gemm1_k<true ><<<dim3(IDIM / 128, NTILE), 256, 0, stream>>>(xb, w3b, g, h, btok, counts, offp);
  gemm2_k<<<dim3(HDIM / 128, NTILE), 256, 0, stream>>>(h, w2b, y, bw, offp);
  combine_k<<<T_TOK, 256, 0, stream>>>(y, pos_of, out);
}

// Round 3
// 721.310 us; speedup vs baseline: 1.3119x; 1.3119x over previous
//
#include <hip/hip_runtime.h>
#include <cstdint>
#include <cstddef>

// Problem constants (from setup_inputs)
#define T_TOK 8192
#define HDIM  2048
#define NEXP  8
#define IDIM  1024
#define CAP   17408   // 16384 assignments + 8*127 padding, rounded to 128
#define NTILE (CAP / 128)   // 136 padded slot-tiles max
#define LTOK  16            // tokens per logits block

typedef __attribute__((ext_vector_type(8))) __bf16 bf16x8;
typedef __attribute__((ext_vector_type(4))) __bf16 bf16x4;
typedef __attribute__((ext_vector_type(4))) float  f32x4;

// async global->LDS, 16B/lane. LDS dest = wave-uniform base + lane*16.
#define GLDS16(g, l)                                                        \
  __builtin_amdgcn_global_load_lds(                                         \
      (__attribute__((address_space(1))) void*)(g),                         \
      (__attribute__((address_space(3))) void*)(l), 16, 0, 0)

// ---------------------------------------------------------------------------
// fp32 -> bf16 bulk convert (weights)
__global__ __launch_bounds__(256) void cvt_k(const float* __restrict__ src,
                                             __bf16* __restrict__ dst, int n4) {
  int i = blockIdx.x * blockDim.x + threadIdx.x;
  int stride = gridDim.x * blockDim.x;
  for (; i < n4; i += stride) {
    float4 v = ((const float4*)src)[i];
    bf16x4 b;
    b[0] = (__bf16)v.x; b[1] = (__bf16)v.y; b[2] = (__bf16)v.z; b[3] = (__bf16)v.w;
    ((bf16x4*)dst)[i] = b;
  }
}

// ---------------------------------------------------------------------------
// Logits + top-2: wg staged in LDS (64 KB fp32), one wave per token (4 tokens
// sequential per wave), fp64 accumulation, NO global atomics. Fuses the
// fp32->bf16 cast of x.
__global__ __launch_bounds__(256) void logits_k(
    const float* __restrict__ x, const float* __restrict__ wg,
    __bf16* __restrict__ xb, int* __restrict__ tok_idx,
    float* __restrict__ tok_w) {
  __shared__ float wgs[NEXP * HDIM];   // 64 KB
  {
    const float4* wg4 = (const float4*)wg;
    float4* wgs4 = (float4*)wgs;
    for (int i = threadIdx.x; i < NEXP * HDIM / 4; i += 256) wgs4[i] = wg4[i];
  }
  __syncthreads();

  const int wid  = threadIdx.x >> 6;
  const int lane = threadIdx.x & 63;

  for (int ti = 0; ti < LTOK / 4; ++ti) {
    const int t = blockIdx.x * LTOK + wid * (LTOK / 4) + ti;
    const float4* x4 = (const float4*)(x + (size_t)t * HDIM);
    bf16x4* xb4 = (bf16x4*)(xb + (size_t)t * HDIM);

    double acc[NEXP];
#pragma unroll
    for (int e = 0; e < NEXP; ++e) acc[e] = 0.0;

#pragma unroll
    for (int j = 0; j < 8; ++j) {
      int idx = j * 64 + lane;          // float4 index (512 per row)
      float4 xv = x4[idx];
      bf16x4 b;
      b[0] = (__bf16)xv.x; b[1] = (__bf16)xv.y; b[2] = (__bf16)xv.z; b[3] = (__bf16)xv.w;
      xb4[idx] = b;
#pragma unroll
      for (int e = 0; e < NEXP; ++e) {
        float4 wv = ((const float4*)(wgs + e * HDIM))[idx];
        acc[e] += (double)xv.x * wv.x + (double)xv.y * wv.y +
                  (double)xv.z * wv.z + (double)xv.w * wv.w;
      }
    }
#pragma unroll
    for (int off = 32; off > 0; off >>= 1)
#pragma unroll
      for (int e = 0; e < NEXP; ++e) acc[e] += __shfl_xor(acc[e], off, 64);

    if (lane == 0) {
      int i0 = 0; double m0 = acc[0];
      for (int e = 1; e < NEXP; ++e) if (acc[e] > m0) { m0 = acc[e]; i0 = e; }
      int i1 = -1; double m1 = -1e300;
      for (int e = 0; e < NEXP; ++e)
        if (e != i0 && acc[e] > m1) { m1 = acc[e]; i1 = e; }
      double p0 = 1.0 / (1.0 + exp(m1 - m0));   // renorm: denominators cancel
      tok_idx[t * 2 + 0] = i0;  tok_idx[t * 2 + 1] = i1;
      tok_w[t * 2 + 0] = (float)p0;
      tok_w[t * 2 + 1] = (float)(1.0 - p0);
    }
  }
}

// ---------------------------------------------------------------------------
// LDS-aggregated histogram: 32 blocks x 256 tokens -> 8 global atomics/block
__global__ __launch_bounds__(256) void hist_k(const int* __restrict__ tok_idx,
                                              int* __restrict__ counts) {
  __shared__ int h[NEXP];
  if (threadIdx.x < NEXP) h[threadIdx.x] = 0;
  __syncthreads();
  int t = blockIdx.x * blockDim.x + threadIdx.x;
  atomicAdd(&h[tok_idx[t * 2 + 0]], 1);
  atomicAdd(&h[tok_idx[t * 2 + 1]], 1);
  __syncthreads();
  if (threadIdx.x < NEXP) atomicAdd(&counts[threadIdx.x], h[threadIdx.x]);
}

// ---------------------------------------------------------------------------
// Padded exclusive scan of counts. offp[NEXP] = total padded slots.
__global__ void offsets_k(const int* __restrict__ counts, int* __restrict__ offp,
                          int* __restrict__ ctr2) {
  if (threadIdx.x == 0) {
    int off = 0;
    for (int e = 0; e < NEXP; ++e) { offp[e] = off; off += (counts[e] + 127) & ~127; }
    offp[NEXP] = off;
  }
  if (threadIdx.x < NEXP) ctr2[threadIdx.x] = 0;
}

// ---------------------------------------------------------------------------
// Bucket scatter with LDS ranking: per block, local ranks via LDS atomics,
// one chunk-reservation global atomic per expert per block (8 x 32 total).
__global__ __launch_bounds__(256) void assign_k(
    const int* __restrict__ tok_idx, const float* __restrict__ tok_w,
    const int* __restrict__ offp, int* __restrict__ ctr2,
    int* __restrict__ btok, float* __restrict__ bw, int* __restrict__ pos_of) {
  __shared__ int lcnt[NEXP], lbase[NEXP];
  if (threadIdx.x < NEXP) lcnt[threadIdx.x] = 0;
  __syncthreads();
  const int t  = blockIdx.x * blockDim.x + threadIdx.x;
  const int e0 = tok_idx[t * 2 + 0];
  const int e1 = tok_idx[t * 2 + 1];
  const int r0 = atomicAdd(&lcnt[e0], 1);
  const int r1 = atomicAdd(&lcnt[e1], 1);
  __syncthreads();
  if (threadIdx.x < NEXP)
    lbase[threadIdx.x] = atomicAdd(&ctr2[threadIdx.x], lcnt[threadIdx.x]);
  __syncthreads();
  int p0 = offp[e0] + lbase[e0] + r0;
  int p1 = offp[e1] + lbase[e1] + r1;
  btok[p0] = t;  bw[p0] = tok_w[t * 2 + 0];  pos_of[t * 2 + 0] = p0;
  btok[p1] = t;  bw[p1] = tok_w[t * 2 + 1];  pos_of[t * 2 + 1] = p1;
}

// ---------------------------------------------------------------------------
// Map a padded-slot tile (128 rows) to its expert. Returns -1 if out of range.
__device__ __forceinline__ int tile_expert(const int* offp, int slot0) {
  if (slot0 >= offp[NEXP]) return -1;
  int e = 0;
#pragma unroll
  for (int i = 1; i < NEXP; ++i) if (offp[i] <= slot0) e = i;
  return e;
}

// ---------------------------------------------------------------------------
// GEMM1 (fused): gathered X [128 x K2048] x (w1,w3 tiles [128 x K]) -> dual
// accumulators; epilogue h = silu(g)*u in registers. A-staging amortized
// across both B matrices (this beat the split version by ~70 us).
__global__ __launch_bounds__(256, 2) void gemm1_k(
    const __bf16* __restrict__ xb, const __bf16* __restrict__ w1b,
    const __bf16* __restrict__ w3b, __bf16* __restrict__ h,
    const int* __restrict__ btok, const int* __restrict__ counts,
    const int* __restrict__ offp) {
  const int mt    = blockIdx.y;
  const int slot0 = mt * 128;
  const int e     = tile_expert(offp, slot0);
  if (e < 0) return;
  const int cnt  = counts[e];
  const int base = offp[e];
  const int mrow = slot0 - base;
  const int it   = blockIdx.x;            // 128 i-values per block

  __shared__ __align__(16) __bf16 As [128 * 32];
  __shared__ __align__(16) __bf16 B1s[128 * 32];
  __shared__ __align__(16) __bf16 B3s[128 * 32];

  const int tid  = threadIdx.x;
  const int lane = tid & 63;
  const int wid  = tid >> 6;
  const int wy   = wid >> 1, wx = wid & 1;

  const int r0 = tid >> 2;
  const int c8 = (tid & 3) * 8;
  int ma = mrow + r0, mb = ma + 64;
  int toka = btok[base + (ma < cnt ? ma : cnt - 1)];
  int tokb = btok[base + (mb < cnt ? mb : cnt - 1)];
  const __bf16* pA0  = xb + (size_t)toka * HDIM + c8;
  const __bf16* pA1  = xb + (size_t)tokb * HDIM + c8;
  const __bf16* pB1a = w1b + ((size_t)e * IDIM + it * 128 + r0) * HDIM + c8;
  const __bf16* pB1b = pB1a + (size_t)64 * HDIM;
  const __bf16* pB3a = w3b + ((size_t)e * IDIM + it * 128 + r0) * HDIM + c8;
  const __bf16* pB3b = pB3a + (size_t)64 * HDIM;

  const int wbase = wid * 512;
  __bf16* lA0  = As  + wbase;  __bf16* lA1  = As  + 2048 + wbase;
  __bf16* lB1a = B1s + wbase;  __bf16* lB1b = B1s + 2048 + wbase;
  __bf16* lB3a = B3s + wbase;  __bf16* lB3b = B3s + 2048 + wbase;

  f32x4 accg[4][4] = {};
  f32x4 accu[4][4] = {};
  const int frow = lane & 15;
  const int fk   = (lane >> 4) * 8;

  for (int kt = 0; kt < HDIM / 32; ++kt) {
    GLDS16(pA0, lA0);   GLDS16(pA1, lA1);
    GLDS16(pB1a, lB1a); GLDS16(pB1b, lB1b);
    GLDS16(pB3a, lB3a); GLDS16(pB3b, lB3b);
    pA0 += 32; pA1 += 32; pB1a += 32; pB1b += 32; pB3a += 32; pB3b += 32;
    __syncthreads();

    bf16x8 af[4], bf1[4], bf3[4];
#pragma unroll
    for (int mf = 0; mf < 4; ++mf)
      af[mf] = *(const bf16x8*)&As[(wy * 64 + mf * 16 + frow) * 32 + fk];
#pragma unroll
    for (int nf = 0; nf < 4; ++nf) {
      bf1[nf] = *(const bf16x8*)&B1s[(wx * 64 + nf * 16 + frow) * 32 + fk];
      bf3[nf] = *(const bf16x8*)&B3s[(wx * 64 + nf * 16 + frow) * 32 + fk];
    }
#pragma unroll
    for (int mf = 0; mf < 4; ++mf)
#pragma unroll
      for (int nf = 0; nf < 4; ++nf) {
        accg[mf][nf] = __builtin_amdgcn_mfma_f32_16x16x32_bf16(af[mf], bf1[nf], accg[mf][nf], 0, 0, 0);
        accu[mf][nf] = __builtin_amdgcn_mfma_f32_16x16x32_bf16(af[mf], bf3[nf], accu[mf][nf], 0, 0, 0);
      }
    __syncthreads();
  }

  const int i0c = it * 128 + wx * 64;
#pragma unroll
  for (int mf = 0; mf < 4; ++mf) {
    const int sbase = slot0 + wy * 64 + mf * 16 + (lane >> 4) * 4;
#pragma unroll
    for (int nf = 0; nf < 4; ++nf) {
      const int ic = i0c + nf * 16 + (lane & 15);
#pragma unroll
      for (int ri = 0; ri < 4; ++ri) {
        int s = sbase + ri;
        if (s - base < cnt) {
          float g = accg[mf][nf][ri];
          float u = accu[mf][nf][ri];
          float sv = g / (1.0f + __expf(-g)) * u;
          h[(size_t)s * IDIM + ic] = (__bf16)sv;
        }
      }
    }
  }
}

// ---------------------------------------------------------------------------
// GEMM2: h [128 x K1024] x w2 tile [128 x K1024] -> y[slot] = w * acc (bf16)
__global__ __launch_bounds__(256) void gemm2_k(
    const __bf16* __restrict__ h, const __bf16* __restrict__ w2b,
    __bf16* __restrict__ y, const float* __restrict__ bw,
    const int* __restrict__ offp) {
  const int mt    = blockIdx.y;
  const int slot0 = mt * 128;
  const int e     = tile_expert(offp, slot0);
  if (e < 0) return;
  const int nt = blockIdx.x;     // 128 H-cols per block

  __shared__ __align__(16) __bf16 As[128 * 32];
  __shared__ __align__(16) __bf16 Bs[128 * 32];

  const int tid  = threadIdx.x;
  const int lane = tid & 63;
  const int wid  = tid >> 6;
  const int wy   = wid >> 1, wx = wid & 1;

  const int r0 = tid >> 2;
  const int c8 = (tid & 3) * 8;
  const __bf16* pA0 = h + ((size_t)slot0 + r0) * IDIM + c8;
  const __bf16* pA1 = pA0 + (size_t)64 * IDIM;
  const __bf16* pB0 = w2b + ((size_t)e * HDIM + nt * 128 + r0) * IDIM + c8;
  const __bf16* pB1 = pB0 + (size_t)64 * IDIM;

  const int wbase = wid * 512;
  __bf16* lA0 = As + wbase;  __bf16* lA1 = As + 2048 + wbase;
  __bf16* lB0 = Bs + wbase;  __bf16* lB1 = Bs + 2048 + wbase;

  f32x4 acc[4][4] = {};
  const int frow = lane & 15;
  const int fk   = (lane >> 4) * 8;

  for (int kt = 0; kt < IDIM / 32; ++kt) {
    GLDS16(pA0, lA0); GLDS16(pA1, lA1);
    GLDS16(pB0, lB0); GLDS16(pB1, lB1);
    pA0 += 32; pA1 += 32; pB0 += 32; pB1 += 32;
    __syncthreads();

    bf16x8 af[4], bf[4];
#pragma unroll
    for (int mf = 0; mf < 4; ++mf)
      af[mf] = *(const bf16x8*)&As[(wy * 64 + mf * 16 + frow) * 32 + fk];
#pragma unroll
    for (int nf = 0; nf < 4; ++nf)
      bf[nf] = *(const bf16x8*)&Bs[(wx * 64 + nf * 16 + frow) * 32 + fk];
#pragma unroll
    for (int mf = 0; mf < 4; ++mf)
#pragma unroll
      for (int nf = 0; nf < 4; ++nf)
        acc[mf][nf] = __builtin_amdgcn_mfma_f32_16x16x32_bf16(af[mf], bf[nf], acc[mf][nf], 0, 0, 0);
    __syncthreads();
  }

  const int ncol = nt * 128 + wx * 64;
#pragma unroll
  for (int mf = 0; mf < 4; ++mf) {
    const int sbase = slot0 + wy * 64 + mf * 16 + (lane >> 4) * 4;
#pragma unroll
    for (int ri = 0; ri < 4; ++ri) {
      int s = sbase + ri;
      float w = bw[s];   // padded slots: garbage but finite; never combined
#pragma unroll
      for (int nf = 0; nf < 4; ++nf) {
        int c = ncol + nf * 16 + (lane & 15);
        y[(size_t)s * HDIM + c] = (__bf16)(acc[mf][nf][ri] * w);
      }
    }
  }
}

// ---------------------------------------------------------------------------
// out[t] = y[pos0[t]] + y[pos1[t]]
__global__ __launch_bounds__(256) void combine_k(
    const __bf16* __restrict__ y, const int* __restrict__ pos_of,
    float* __restrict__ out) {
  const int t  = blockIdx.x;
  const int c8 = threadIdx.x * 8;
  const int p0 = pos_of[t * 2 + 0];
  const int p1 = pos_of[t * 2 + 1];
  bf16x8 a = *(const bf16x8*)&y[(size_t)p0 * HDIM + c8];
  bf16x8 b = *(const bf16x8*)&y[(size_t)p1 * HDIM + c8];
  float4 o0, o1;
  o0.x = (float)a[0] + (float)b[0];  o0.y = (float)a[1] + (float)b[1];
  o0.z = (float)a[2] + (float)b[2];  o0.w = (float)a[3] + (float)b[3];
  o1.x = (float)a[4] + (float)b[4];  o1.y = (float)a[5] + (float)b[5];
  o1.z = (float)a[6] + (float)b[6];  o1.w = (float)a[7] + (float)b[7];
  float* op = out + (size_t)t * HDIM + c8;
  *(float4*)op = o0;
  *(float4*)(op + 4) = o1;
}

// ---------------------------------------------------------------------------
extern "C" void kernel_launch(void* const* d_in, const int* in_sizes, int n_in,
                              void* d_out, int out_size, void* d_ws, size_t ws_size,
                              hipStream_t stream) {
  (void)in_sizes; (void)n_in; (void)out_size; (void)ws_size;
  const float* x  = (const float*)d_in[0];
  const float* wg = (const float*)d_in[1];
  const float* w1 = (const float*)d_in[2];
  const float* w3 = (const float*)d_in[3];
  const float* w2 = (const float*)d_in[4];
  float* out = (float*)d_out;

  char* ws = (char*)d_ws;
  size_t off = 0;
  auto alloc = [&](size_t bytes) -> char* {
    char* p = ws + off;
    off += (bytes + 255) & ~(size_t)255;
    return p;
  };
  __bf16* xb      = (__bf16*)alloc((size_t)T_TOK * HDIM * 2);          // 33.5 MB
  __bf16* w1b     = (__bf16*)alloc((size_t)NEXP * IDIM * HDIM * 2);    // 33.5 MB
  __bf16* w3b     = (__bf16*)alloc((size_t)NEXP * IDIM * HDIM * 2);    // 33.5 MB
  __bf16* w2b     = (__bf16*)alloc((size_t)NEXP * HDIM * IDIM * 2);    // 33.5 MB
  __bf16* h       = (__bf16*)alloc((size_t)CAP * IDIM * 2);            // 35.7 MB
  __bf16* y       = (__bf16*)alloc((size_t)CAP * HDIM * 2);            // 71.3 MB
  int*    btok    = (int*)alloc((size_t)CAP * 4);
  float*  bw      = (float*)alloc((size_t)CAP * 4);
  int*    pos_of  = (int*)alloc((size_t)T_TOK * 2 * 4);
  int*    tok_idx = (int*)alloc((size_t)T_TOK * 2 * 4);
  float*  tok_w   = (float*)alloc((size_t)T_TOK * 2 * 4);
  int*    counts  = (int*)alloc(256);
  int*    ctr2    = (int*)alloc(256);
  int*    offp    = (int*)alloc(256);
  // total ws ~ 242 MB

  hipMemsetAsync(counts, 0, 768, stream);                 // counts+ctr2+offp

  const int n4w = NEXP * IDIM * HDIM / 4;
  cvt_k<<<2048, 256, 0, stream>>>(w1, w1b, n4w);
  cvt_k<<<2048, 256, 0, stream>>>(w3, w3b, n4w);
  cvt_k<<<2048, 256, 0, stream>>>(w2, w2b, n4w);

  logits_k<<<T_TOK / LTOK, 256, 0, stream>>>(x, wg, xb, tok_idx, tok_w);
  hist_k<<<T_TOK / 256, 256, 0, stream>>>(tok_idx, counts);
  offsets_k<<<1, 64, 0, stream>>>(counts, offp, ctr2);
  assign_k<<<T_TOK / 256, 256, 0, stream>>>(tok_idx, tok_w, offp, ctr2, btok, bw, pos_of);

  gemm1_k<<<dim3(IDIM / 128, NTILE), 256, 0, stream>>>(xb, w1b, w3b, h, btok, counts, offp);
  gemm2_k<<<dim3(HDIM / 128, NTILE), 256, 0, stream>>>(h, w2b, y, bw, offp);
  combine_k<<<T_TOK, 256, 0, stream>>>(y, pos_of, out);
}